// Round 1
// baseline (5855.361 us; speedup 1.0000x reference)
//
#include <hip/hip_runtime.h>
#include <math.h>

#define D 128

// ---------------------------------------------------------------------------
// Prep: build combined transposed weight matrix WT[256][128]:
//   WT[k][c] = w_l[c][k]        for k < 128   (agg part)
//   WT[k][c] = w_r[c][k-128]    for k >= 128  (self part)
// so out[n][c] = sum_k row[n][k] * WT[k][c],  row = [agg | x].
// ---------------------------------------------------------------------------
__global__ void prep_weights(const float* __restrict__ wl,
                             const float* __restrict__ wr,
                             float* __restrict__ WT) {
    int idx = blockIdx.x * 256 + threadIdx.x;  // 256*128 elements
    if (idx >= 256 * 128) return;
    int k = idx >> 7;
    int c = idx & 127;
    WT[idx] = (k < 128) ? wl[c * 128 + k] : wr[c * 128 + (k - 128)];
}

// ---------------------------------------------------------------------------
// Edge scatter: 32 threads per edge, 4 dims each (float4 gather, 4 atomics).
// summed[dst] += x[src]; cnt[dst] += 1.
// ---------------------------------------------------------------------------
__global__ __launch_bounds__(256) void scatter_edges(
        const float* __restrict__ x, const int* __restrict__ ei, int E,
        float* __restrict__ summed, float* __restrict__ cnt) {
    int t = blockIdx.x * 256 + threadIdx.x;
    int e = t >> 5;
    if (e >= E) return;
    int lane = t & 31;
    int src = ei[e];        // row 0 of [2,E]
    int dst = ei[E + e];    // row 1 of [2,E]
    float4 v = *(const float4*)(x + src * D + lane * 4);
    float* o = summed + dst * D + lane * 4;
    atomicAdd(o + 0, v.x);
    atomicAdd(o + 1, v.y);
    atomicAdd(o + 2, v.z);
    atomicAdd(o + 3, v.w);
    if (lane == 0) atomicAdd(cnt + dst, 1.0f);
}

// ---------------------------------------------------------------------------
// Fused SAGE linear: out[n] = [summed[n]/max(cnt,1) | x[n]] @ WT + b, opt GELU.
// Block = 256 threads, 128 nodes/block. Thread (ti = tid>>4, tj = tid&15)
// computes 8 nodes {ti + 16*i} x 8 cols {tj*4+j, 64+tj*4+j}.
//  - row_lds stride 36 (pad 4): row reads for ti,ti+1,ti+2,ti+3 land 4 banks
//    apart -> conflict-free float4 reads.
//  - w cols split into two 64-halves: tj*4 strides -> 2-way (free).
// ---------------------------------------------------------------------------
template <bool GELU>
__global__ __launch_bounds__(256) void sage_linear(
        const float* __restrict__ summed, const float* __restrict__ cnt,
        const float* __restrict__ x, const float* __restrict__ WT,
        const float* __restrict__ bias, float* __restrict__ out, int N) {
    __shared__ float w_lds[32][128];
    __shared__ float row_lds[128][36];
    __shared__ float inv_lds[128];

    const int tid = threadIdx.x;
    const int n0 = blockIdx.x * 128;
    const int tj = tid & 15;
    const int ti = tid >> 4;
    const int cA = tj * 4;
    const int cB = 64 + tj * 4;

    if (tid < 128) {
        int gn = n0 + tid;
        float c = (gn < N) ? cnt[gn] : 1.0f;
        inv_lds[tid] = 1.0f / fmaxf(c, 1.0f);
    }

    float acc[8][8];
#pragma unroll
    for (int i = 0; i < 8; ++i)
#pragma unroll
        for (int j = 0; j < 8; ++j) acc[i][j] = 0.0f;

    for (int k0 = 0; k0 < 256; k0 += 32) {
        const bool is_agg = (k0 < 128);
        const float* sm = is_agg ? (summed + k0) : (x + (k0 - 128));

        __syncthreads();  // previous tile fully consumed (also covers inv_lds)

        // load W tile [32 k][128 c]: 16 floats/thread, coalesced
        {
            int c4 = tid & 31;      // float4 col index
            int kk = tid >> 5;      // 8 k per pass
#pragma unroll
            for (int p = 0; p < 4; ++p) {
                int k = kk + p * 8;
                float4 wv = *(const float4*)(WT + (k0 + k) * 128 + c4 * 4);
                *(float4*)&w_lds[k][c4 * 4] = wv;
            }
        }
        // load row tile [128 n][32 k]
        {
            int kq = tid & 7;       // float4 k index
            int nl = tid >> 3;      // 32 nodes per pass
#pragma unroll
            for (int p = 0; p < 4; ++p) {
                int n = nl + p * 32;
                int gn = n0 + n;
                float4 v = make_float4(0.f, 0.f, 0.f, 0.f);
                if (gn < N) v = *(const float4*)(sm + gn * D + kq * 4);
                if (is_agg) {
                    float s = inv_lds[n];
                    v.x *= s; v.y *= s; v.z *= s; v.w *= s;
                }
                *(float4*)&row_lds[n][kq * 4] = v;
            }
        }
        __syncthreads();

        for (int k = 0; k < 32; k += 4) {
            float4 rv[8];
#pragma unroll
            for (int i = 0; i < 8; ++i)
                rv[i] = *(const float4*)&row_lds[ti + 16 * i][k];
#pragma unroll
            for (int kk = 0; kk < 4; ++kk) {
                float4 wa = *(const float4*)&w_lds[k + kk][cA];
                float4 wb = *(const float4*)&w_lds[k + kk][cB];
#pragma unroll
                for (int i = 0; i < 8; ++i) {
                    float r = ((const float*)&rv[i])[kk];
                    acc[i][0] += r * wa.x;
                    acc[i][1] += r * wa.y;
                    acc[i][2] += r * wa.z;
                    acc[i][3] += r * wa.w;
                    acc[i][4] += r * wb.x;
                    acc[i][5] += r * wb.y;
                    acc[i][6] += r * wb.z;
                    acc[i][7] += r * wb.w;
                }
            }
        }
    }

    // epilogue: + bias, optional exact GELU, store
    float4 ba = *(const float4*)&bias[cA];
    float4 bb = *(const float4*)&bias[cB];
#pragma unroll
    for (int i = 0; i < 8; ++i) {
        int gn = n0 + ti + 16 * i;
        if (gn >= N) continue;
        float o[8];
        o[0] = acc[i][0] + ba.x; o[1] = acc[i][1] + ba.y;
        o[2] = acc[i][2] + ba.z; o[3] = acc[i][3] + ba.w;
        o[4] = acc[i][4] + bb.x; o[5] = acc[i][5] + bb.y;
        o[6] = acc[i][6] + bb.z; o[7] = acc[i][7] + bb.w;
        if (GELU) {
#pragma unroll
            for (int j = 0; j < 8; ++j)
                o[j] = 0.5f * o[j] * (1.0f + erff(o[j] * 0.70710678118654752f));
        }
        float4 oa = make_float4(o[0], o[1], o[2], o[3]);
        float4 ob = make_float4(o[4], o[5], o[6], o[7]);
        *(float4*)&out[gn * D + cA] = oa;
        *(float4*)&out[gn * D + cB] = ob;
    }
}

// ---------------------------------------------------------------------------
extern "C" void kernel_launch(void* const* d_in, const int* in_sizes, int n_in,
                              void* d_out, int out_size, void* d_ws, size_t ws_size,
                              hipStream_t stream) {
    const float* embs = (const float*)d_in[0];
    const int*   ei0  = (const int*)d_in[1];
    const int*   ei1  = (const int*)d_in[2];
    const float* w_l0 = (const float*)d_in[3];
    const float* w_r0 = (const float*)d_in[4];
    const float* b0   = (const float*)d_in[5];
    const float* w_l1 = (const float*)d_in[6];
    const float* w_r1 = (const float*)d_in[7];
    const float* b1   = (const float*)d_in[8];
    float* out = (float*)d_out;

    const int N = in_sizes[0] / D;
    const int E = in_sizes[1] / 2;

    // ws layout: summed [N*D] | cnt [N] | h [N*D] | WT0 [256*128] | WT1 [256*128]
    float* summed = (float*)d_ws;
    float* cnt    = summed + (size_t)N * D;
    float* h      = cnt + N;
    float* WT0    = h + (size_t)N * D;
    float* WT1    = WT0 + 256 * 128;

    const int prep_grid = (256 * 128 + 255) / 256;
    prep_weights<<<prep_grid, 256, 0, stream>>>(w_l0, w_r0, WT0);
    prep_weights<<<prep_grid, 256, 0, stream>>>(w_l1, w_r1, WT1);

    const size_t zero_bytes = ((size_t)N * D + N) * sizeof(float);
    const int scat_grid = (E * 32 + 255) / 256;
    const int gemm_grid = (N + 127) / 128;

    // ---- layer 0 ----
    hipMemsetAsync(summed, 0, zero_bytes, stream);
    scatter_edges<<<scat_grid, 256, 0, stream>>>(embs, ei0, E, summed, cnt);
    sage_linear<true><<<gemm_grid, 256, 0, stream>>>(summed, cnt, embs, WT0, b0, h, N);

    // ---- layer 1 ----
    hipMemsetAsync(summed, 0, zero_bytes, stream);
    scatter_edges<<<scat_grid, 256, 0, stream>>>(h, ei1, E, summed, cnt);
    sage_linear<false><<<gemm_grid, 256, 0, stream>>>(summed, cnt, h, WT1, b1, out, N);
}

// Round 2
// 1353.841 us; speedup vs baseline: 4.3250x; 4.3250x over previous
//
#include <hip/hip_runtime.h>
#include <math.h>

#define D 128
#define SCAN_T 1024

// ---------------------------------------------------------------------------
// Prep: combined transposed weight WT[256][128]:
//   WT[k][c] = w_l[c][k] (k<128) else w_r[c][k-128]
// out[n][c] = sum_k [agg[n] | x[n]][k] * WT[k][c]
// ---------------------------------------------------------------------------
__global__ void prep_weights(const float* __restrict__ wl,
                             const float* __restrict__ wr,
                             float* __restrict__ WT) {
    int idx = blockIdx.x * 256 + threadIdx.x;
    if (idx >= 256 * 128) return;
    int k = idx >> 7;
    int c = idx & 127;
    WT[idx] = (k < 128) ? wl[c * 128 + k] : wr[c * 128 + (k - 128)];
}

// ---------------------------------------------------------------------------
// CSR build step 1: histogram of dst degrees into cursor (pre-zeroed).
// ---------------------------------------------------------------------------
__global__ __launch_bounds__(256) void hist_kernel(
        const int* __restrict__ ei, int E, int* __restrict__ cursor) {
    int e = blockIdx.x * 256 + threadIdx.x;
    if (e >= E) return;
    atomicAdd(&cursor[ei[E + e]], 1);
}

// ---------------------------------------------------------------------------
// CSR build step 2: single-block exclusive scan.
// In: cursor = counts. Out: row_ptr[0..N] = prefix, cursor = start offsets.
// ---------------------------------------------------------------------------
__global__ __launch_bounds__(SCAN_T) void scan_kernel(
        int* __restrict__ cursor, int* __restrict__ row_ptr, int N) {
    __shared__ int part[SCAN_T];
    int t = threadIdx.x;
    int chunk = (N + SCAN_T - 1) / SCAN_T;
    int b = t * chunk;
    int e = min(b + chunk, N);
    int s = 0;
    for (int i = b; i < e; ++i) s += cursor[i];
    part[t] = s;
    __syncthreads();
    // Hillis-Steele inclusive scan
    for (int off = 1; off < SCAN_T; off <<= 1) {
        int v = (t >= off) ? part[t - off] : 0;
        __syncthreads();
        part[t] += v;
        __syncthreads();
    }
    int run = (t == 0) ? 0 : part[t - 1];  // exclusive prefix for this chunk
    for (int i = b; i < e; ++i) {
        int c = cursor[i];
        row_ptr[i] = run;
        cursor[i] = run;
        run += c;
    }
    if (t == 0) row_ptr[N] = part[SCAN_T - 1];
}

// ---------------------------------------------------------------------------
// CSR build step 3: scatter src ids into dst buckets.
// ---------------------------------------------------------------------------
__global__ __launch_bounds__(256) void fill_kernel(
        const int* __restrict__ ei, int E,
        int* __restrict__ cursor, int* __restrict__ edge_src) {
    int e = blockIdx.x * 256 + threadIdx.x;
    if (e >= E) return;
    int src = ei[e];
    int dst = ei[E + e];
    int pos = atomicAdd(&cursor[dst], 1);
    edge_src[pos] = src;
}

// ---------------------------------------------------------------------------
// Gather aggregation: one 64-lane wave per node, lane holds float2 of dims.
// agg[n] = mean_{src in csr[n]} x[src]  (0 for isolated nodes).
// row_ptr/edge_src reads are wave-uniform -> scalar loads; x gather is one
// coalesced 512 B read per edge. Unroll-4 for memory-level parallelism.
// ---------------------------------------------------------------------------
__global__ __launch_bounds__(256) void agg_kernel(
        const float* __restrict__ x, const int* __restrict__ row_ptr,
        const int* __restrict__ edge_src, float* __restrict__ agg, int N) {
    int gt = blockIdx.x * 256 + threadIdx.x;
    int w = gt >> 6;         // node id
    int lane = gt & 63;
    if (w >= N) return;
    int beg = row_ptr[w];
    int end = row_ptr[w + 1];
    const float* base = x + lane * 2;
    float ax = 0.0f, ay = 0.0f;
    int e = beg;
    for (; e + 4 <= end; e += 4) {
        int s0 = edge_src[e + 0];
        int s1 = edge_src[e + 1];
        int s2 = edge_src[e + 2];
        int s3 = edge_src[e + 3];
        float2 v0 = *(const float2*)(base + (size_t)s0 * D);
        float2 v1 = *(const float2*)(base + (size_t)s1 * D);
        float2 v2 = *(const float2*)(base + (size_t)s2 * D);
        float2 v3 = *(const float2*)(base + (size_t)s3 * D);
        ax += v0.x + v1.x + v2.x + v3.x;
        ay += v0.y + v1.y + v2.y + v3.y;
    }
    for (; e < end; ++e) {
        float2 v = *(const float2*)(base + (size_t)edge_src[e] * D);
        ax += v.x;
        ay += v.y;
    }
    int deg = end - beg;
    float inv = (deg > 0) ? 1.0f / (float)deg : 0.0f;
    float2 o = make_float2(ax * inv, ay * inv);
    *(float2*)(agg + (size_t)w * D + lane * 2) = o;
}

// ---------------------------------------------------------------------------
// Fused SAGE linear: out[n] = [agg[n] | x[n]] @ WT + b, optional exact GELU.
// Block = 256 threads, 128 nodes/block; thread computes 8 nodes x 8 cols.
// ---------------------------------------------------------------------------
template <bool GELU>
__global__ __launch_bounds__(256) void sage_linear(
        const float* __restrict__ agg, const float* __restrict__ x,
        const float* __restrict__ WT, const float* __restrict__ bias,
        float* __restrict__ out, int N) {
    __shared__ float w_lds[32][128];
    __shared__ float row_lds[128][36];

    const int tid = threadIdx.x;
    const int n0 = blockIdx.x * 128;
    const int tj = tid & 15;
    const int ti = tid >> 4;
    const int cA = tj * 4;
    const int cB = 64 + tj * 4;

    float acc[8][8];
#pragma unroll
    for (int i = 0; i < 8; ++i)
#pragma unroll
        for (int j = 0; j < 8; ++j) acc[i][j] = 0.0f;

    for (int k0 = 0; k0 < 256; k0 += 32) {
        const float* sm = (k0 < 128) ? (agg + k0) : (x + (k0 - 128));

        __syncthreads();  // previous tile fully consumed

        // W tile [32 k][128 c]
        {
            int c4 = tid & 31;
            int kk = tid >> 5;
#pragma unroll
            for (int p = 0; p < 4; ++p) {
                int k = kk + p * 8;
                float4 wv = *(const float4*)(WT + (k0 + k) * 128 + c4 * 4);
                *(float4*)&w_lds[k][c4 * 4] = wv;
            }
        }
        // row tile [128 n][32 k]
        {
            int kq = tid & 7;
            int nl = tid >> 3;
#pragma unroll
            for (int p = 0; p < 4; ++p) {
                int n = nl + p * 32;
                int gn = n0 + n;
                float4 v = make_float4(0.f, 0.f, 0.f, 0.f);
                if (gn < N) v = *(const float4*)(sm + (size_t)gn * D + kq * 4);
                *(float4*)&row_lds[n][kq * 4] = v;
            }
        }
        __syncthreads();

        for (int k = 0; k < 32; k += 4) {
            float4 rv[8];
#pragma unroll
            for (int i = 0; i < 8; ++i)
                rv[i] = *(const float4*)&row_lds[ti + 16 * i][k];
#pragma unroll
            for (int kk = 0; kk < 4; ++kk) {
                float4 wa = *(const float4*)&w_lds[k + kk][cA];
                float4 wb = *(const float4*)&w_lds[k + kk][cB];
#pragma unroll
                for (int i = 0; i < 8; ++i) {
                    float r = ((const float*)&rv[i])[kk];
                    acc[i][0] += r * wa.x;
                    acc[i][1] += r * wa.y;
                    acc[i][2] += r * wa.z;
                    acc[i][3] += r * wa.w;
                    acc[i][4] += r * wb.x;
                    acc[i][5] += r * wb.y;
                    acc[i][6] += r * wb.z;
                    acc[i][7] += r * wb.w;
                }
            }
        }
    }

    float4 ba = *(const float4*)&bias[cA];
    float4 bb = *(const float4*)&bias[cB];
#pragma unroll
    for (int i = 0; i < 8; ++i) {
        int gn = n0 + ti + 16 * i;
        if (gn >= N) continue;
        float o[8];
        o[0] = acc[i][0] + ba.x; o[1] = acc[i][1] + ba.y;
        o[2] = acc[i][2] + ba.z; o[3] = acc[i][3] + ba.w;
        o[4] = acc[i][4] + bb.x; o[5] = acc[i][5] + bb.y;
        o[6] = acc[i][6] + bb.z; o[7] = acc[i][7] + bb.w;
        if (GELU) {
#pragma unroll
            for (int j = 0; j < 8; ++j)
                o[j] = 0.5f * o[j] * (1.0f + erff(o[j] * 0.70710678118654752f));
        }
        *(float4*)&out[(size_t)gn * D + cA] = make_float4(o[0], o[1], o[2], o[3]);
        *(float4*)&out[(size_t)gn * D + cB] = make_float4(o[4], o[5], o[6], o[7]);
    }
}

// ---------------------------------------------------------------------------
extern "C" void kernel_launch(void* const* d_in, const int* in_sizes, int n_in,
                              void* d_out, int out_size, void* d_ws, size_t ws_size,
                              hipStream_t stream) {
    const float* embs = (const float*)d_in[0];
    const int*   ei0  = (const int*)d_in[1];
    const int*   ei1  = (const int*)d_in[2];
    const float* w_l0 = (const float*)d_in[3];
    const float* w_r0 = (const float*)d_in[4];
    const float* b0   = (const float*)d_in[5];
    const float* w_l1 = (const float*)d_in[6];
    const float* w_r1 = (const float*)d_in[7];
    const float* b1   = (const float*)d_in[8];
    float* out = (float*)d_out;

    const int N = in_sizes[0] / D;
    const int E = in_sizes[1] / 2;

    // ws layout (floats first, then ints):
    // agg [N*D] | h [N*D] | WT0 [32768] | WT1 [32768] |
    // row_ptr0 [N+1] | cursor0 [N] | edge_src0 [E] |
    // row_ptr1 [N+1] | cursor1 [N] | edge_src1 [E]
    float* agg = (float*)d_ws;
    float* h   = agg + (size_t)N * D;
    float* WT0 = h + (size_t)N * D;
    float* WT1 = WT0 + 256 * 128;
    int* row_ptr0  = (int*)(WT1 + 256 * 128);
    int* cursor0   = row_ptr0 + (N + 1);
    int* edge_src0 = cursor0 + N;
    int* row_ptr1  = edge_src0 + E;
    int* cursor1   = row_ptr1 + (N + 1);
    int* edge_src1 = cursor1 + N;

    const int prep_grid = (256 * 128 + 255) / 256;
    const int edge_grid = (E + 255) / 256;
    const int agg_grid  = ((size_t)N * 64 + 255) / 256;
    const int gemm_grid = (N + 127) / 128;

    prep_weights<<<prep_grid, 256, 0, stream>>>(w_l0, w_r0, WT0);
    prep_weights<<<prep_grid, 256, 0, stream>>>(w_l1, w_r1, WT1);

    // ---- CSR builds (independent of feature data) ----
    hipMemsetAsync(cursor0, 0, (size_t)N * sizeof(int), stream);
    hist_kernel<<<edge_grid, 256, 0, stream>>>(ei0, E, cursor0);
    scan_kernel<<<1, SCAN_T, 0, stream>>>(cursor0, row_ptr0, N);
    fill_kernel<<<edge_grid, 256, 0, stream>>>(ei0, E, cursor0, edge_src0);

    hipMemsetAsync(cursor1, 0, (size_t)N * sizeof(int), stream);
    hist_kernel<<<edge_grid, 256, 0, stream>>>(ei1, E, cursor1);
    scan_kernel<<<1, SCAN_T, 0, stream>>>(cursor1, row_ptr1, N);
    fill_kernel<<<edge_grid, 256, 0, stream>>>(ei1, E, cursor1, edge_src1);

    // ---- layer 0 ----
    agg_kernel<<<agg_grid, 256, 0, stream>>>(embs, row_ptr0, edge_src0, agg, N);
    sage_linear<true><<<gemm_grid, 256, 0, stream>>>(agg, embs, WT0, b0, h, N);

    // ---- layer 1 ----
    agg_kernel<<<agg_grid, 256, 0, stream>>>(h, row_ptr1, edge_src1, agg, N);
    sage_linear<false><<<gemm_grid, 256, 0, stream>>>(agg, h, WT1, b1, out, N);
}

// Round 3
// 958.922 us; speedup vs baseline: 6.1062x; 1.4118x over previous
//
#include <hip/hip_runtime.h>
#include <math.h>

#define D 128
#define SCAN_CHUNK 1024   // counts per block in the device-wide scan

// ---------------------------------------------------------------------------
// Prep: combined transposed weight WT[256][128]:
//   WT[k][c] = w_l[c][k] (k<128) else w_r[c][k-128]
// out[n][c] = sum_k [agg[n] | x[n]][k] * WT[k][c]
// ---------------------------------------------------------------------------
__global__ void prep_weights(const float* __restrict__ wl,
                             const float* __restrict__ wr,
                             float* __restrict__ WT) {
    int idx = blockIdx.x * 256 + threadIdx.x;
    if (idx >= 256 * 128) return;
    int k = idx >> 7;
    int c = idx & 127;
    WT[idx] = (k < 128) ? wl[c * 128 + k] : wr[c * 128 + (k - 128)];
}

// ---------------------------------------------------------------------------
// CSR build step 1: histogram of dst degrees into cursor (pre-zeroed).
// ---------------------------------------------------------------------------
__global__ __launch_bounds__(256) void hist_kernel(
        const int* __restrict__ ei, int E, int* __restrict__ cursor) {
    int e = blockIdx.x * 256 + threadIdx.x;
    if (e >= E) return;
    atomicAdd(&cursor[ei[E + e]], 1);
}

// ---------------------------------------------------------------------------
// Device-wide exclusive scan, 3 phases. nb = ceil(N/SCAN_CHUNK) must be <=256.
// ---------------------------------------------------------------------------
__global__ __launch_bounds__(256) void scan_phase_a(
        const int* __restrict__ counts, int N, int* __restrict__ blk_sums) {
    __shared__ int red[256];
    int t = threadIdx.x;
    int base = blockIdx.x * SCAN_CHUNK + t * 4;
    int s = 0;
#pragma unroll
    for (int i = 0; i < 4; ++i) {
        int idx = base + i;
        if (idx < N) s += counts[idx];
    }
    red[t] = s;
    __syncthreads();
    for (int off = 128; off > 0; off >>= 1) {
        if (t < off) red[t] += red[t + off];
        __syncthreads();
    }
    if (t == 0) blk_sums[blockIdx.x] = red[0];
}

__global__ __launch_bounds__(256) void scan_phase_b(
        int* __restrict__ blk_sums, int nb) {
    __shared__ int part[256];
    int t = threadIdx.x;
    part[t] = (t < nb) ? blk_sums[t] : 0;
    __syncthreads();
    for (int off = 1; off < 256; off <<= 1) {
        int u = (t >= off) ? part[t - off] : 0;
        __syncthreads();
        part[t] += u;
        __syncthreads();
    }
    if (t < nb) blk_sums[t] = (t == 0) ? 0 : part[t - 1];  // exclusive
}

__global__ __launch_bounds__(256) void scan_phase_c(
        int* __restrict__ counts /* in: counts, out: offsets */, int N, int E,
        const int* __restrict__ blk_sums,
        int* __restrict__ row_ptr) {
    __shared__ int part[256];
    int t = threadIdx.x;
    int base = blockIdx.x * SCAN_CHUNK + t * 4;
    int c[4];
    int s = 0;
#pragma unroll
    for (int i = 0; i < 4; ++i) {
        int idx = base + i;
        c[i] = (idx < N) ? counts[idx] : 0;
        s += c[i];
    }
    part[t] = s;
    __syncthreads();
    for (int off = 1; off < 256; off <<= 1) {
        int u = (t >= off) ? part[t - off] : 0;
        __syncthreads();
        part[t] += u;
        __syncthreads();
    }
    int run = blk_sums[blockIdx.x] + ((t == 0) ? 0 : part[t - 1]);
#pragma unroll
    for (int i = 0; i < 4; ++i) {
        int idx = base + i;
        if (idx < N) {
            row_ptr[idx] = run;
            counts[idx] = run;   // becomes the fill cursor
            run += c[i];
        }
    }
    if (blockIdx.x == 0 && t == 0) row_ptr[N] = E;
}

// ---------------------------------------------------------------------------
// CSR build step 3: scatter src ids into dst buckets.
// ---------------------------------------------------------------------------
__global__ __launch_bounds__(256) void fill_kernel(
        const int* __restrict__ ei, int E,
        int* __restrict__ cursor, int* __restrict__ edge_src) {
    int e = blockIdx.x * 256 + threadIdx.x;
    if (e >= E) return;
    int src = ei[e];
    int dst = ei[E + e];
    int pos = atomicAdd(&cursor[dst], 1);
    edge_src[pos] = src;
}

// ---------------------------------------------------------------------------
// Gather aggregation: one 64-lane wave per node, lane holds float2 of dims.
// agg[n] = mean_{src in csr[n]} x[src]  (0 for isolated nodes).
// ---------------------------------------------------------------------------
__global__ __launch_bounds__(256) void agg_kernel(
        const float* __restrict__ x, const int* __restrict__ row_ptr,
        const int* __restrict__ edge_src, float* __restrict__ agg, int N) {
    int gt = blockIdx.x * 256 + threadIdx.x;
    int w = gt >> 6;         // node id
    int lane = gt & 63;
    if (w >= N) return;
    int beg = row_ptr[w];
    int end = row_ptr[w + 1];
    const float* base = x + lane * 2;
    float ax = 0.0f, ay = 0.0f;
    int e = beg;
    for (; e + 4 <= end; e += 4) {
        int s0 = edge_src[e + 0];
        int s1 = edge_src[e + 1];
        int s2 = edge_src[e + 2];
        int s3 = edge_src[e + 3];
        float2 v0 = *(const float2*)(base + (size_t)s0 * D);
        float2 v1 = *(const float2*)(base + (size_t)s1 * D);
        float2 v2 = *(const float2*)(base + (size_t)s2 * D);
        float2 v3 = *(const float2*)(base + (size_t)s3 * D);
        ax += v0.x + v1.x + v2.x + v3.x;
        ay += v0.y + v1.y + v2.y + v3.y;
    }
    for (; e < end; ++e) {
        float2 v = *(const float2*)(base + (size_t)edge_src[e] * D);
        ax += v.x;
        ay += v.y;
    }
    int deg = end - beg;
    float inv = (deg > 0) ? 1.0f / (float)deg : 0.0f;
    *(float2*)(agg + (size_t)w * D + lane * 2) = make_float2(ax * inv, ay * inv);
}

// ---------------------------------------------------------------------------
// Fused SAGE linear: out[n] = [agg[n] | x[n]] @ WT + b, optional exact GELU.
// Block = 256 threads, 128 nodes/block; thread computes 8 nodes x 8 cols.
// ---------------------------------------------------------------------------
template <bool GELU>
__global__ __launch_bounds__(256) void sage_linear(
        const float* __restrict__ agg, const float* __restrict__ x,
        const float* __restrict__ WT, const float* __restrict__ bias,
        float* __restrict__ out, int N) {
    __shared__ float w_lds[32][128];
    __shared__ float row_lds[128][36];

    const int tid = threadIdx.x;
    const int n0 = blockIdx.x * 128;
    const int tj = tid & 15;
    const int ti = tid >> 4;
    const int cA = tj * 4;
    const int cB = 64 + tj * 4;

    float acc[8][8];
#pragma unroll
    for (int i = 0; i < 8; ++i)
#pragma unroll
        for (int j = 0; j < 8; ++j) acc[i][j] = 0.0f;

    for (int k0 = 0; k0 < 256; k0 += 32) {
        const float* sm = (k0 < 128) ? (agg + k0) : (x + (k0 - 128));

        __syncthreads();

        {
            int c4 = tid & 31;
            int kk = tid >> 5;
#pragma unroll
            for (int p = 0; p < 4; ++p) {
                int k = kk + p * 8;
                float4 wv = *(const float4*)(WT + (k0 + k) * 128 + c4 * 4);
                *(float4*)&w_lds[k][c4 * 4] = wv;
            }
        }
        {
            int kq = tid & 7;
            int nl = tid >> 3;
#pragma unroll
            for (int p = 0; p < 4; ++p) {
                int n = nl + p * 32;
                int gn = n0 + n;
                float4 v = make_float4(0.f, 0.f, 0.f, 0.f);
                if (gn < N) v = *(const float4*)(sm + (size_t)gn * D + kq * 4);
                *(float4*)&row_lds[n][kq * 4] = v;
            }
        }
        __syncthreads();

        for (int k = 0; k < 32; k += 4) {
            float4 rv[8];
#pragma unroll
            for (int i = 0; i < 8; ++i)
                rv[i] = *(const float4*)&row_lds[ti + 16 * i][k];
#pragma unroll
            for (int kk = 0; kk < 4; ++kk) {
                float4 wa = *(const float4*)&w_lds[k + kk][cA];
                float4 wb = *(const float4*)&w_lds[k + kk][cB];
#pragma unroll
                for (int i = 0; i < 8; ++i) {
                    float r = ((const float*)&rv[i])[kk];
                    acc[i][0] += r * wa.x;
                    acc[i][1] += r * wa.y;
                    acc[i][2] += r * wa.z;
                    acc[i][3] += r * wa.w;
                    acc[i][4] += r * wb.x;
                    acc[i][5] += r * wb.y;
                    acc[i][6] += r * wb.z;
                    acc[i][7] += r * wb.w;
                }
            }
        }
    }

    float4 ba = *(const float4*)&bias[cA];
    float4 bb = *(const float4*)&bias[cB];
#pragma unroll
    for (int i = 0; i < 8; ++i) {
        int gn = n0 + ti + 16 * i;
        if (gn >= N) continue;
        float o[8];
        o[0] = acc[i][0] + ba.x; o[1] = acc[i][1] + ba.y;
        o[2] = acc[i][2] + ba.z; o[3] = acc[i][3] + ba.w;
        o[4] = acc[i][4] + bb.x; o[5] = acc[i][5] + bb.y;
        o[6] = acc[i][6] + bb.z; o[7] = acc[i][7] + bb.w;
        if (GELU) {
#pragma unroll
            for (int j = 0; j < 8; ++j)
                o[j] = 0.5f * o[j] * (1.0f + erff(o[j] * 0.70710678118654752f));
        }
        *(float4*)&out[(size_t)gn * D + cA] = make_float4(o[0], o[1], o[2], o[3]);
        *(float4*)&out[(size_t)gn * D + cB] = make_float4(o[4], o[5], o[6], o[7]);
    }
}

// ---------------------------------------------------------------------------
extern "C" void kernel_launch(void* const* d_in, const int* in_sizes, int n_in,
                              void* d_out, int out_size, void* d_ws, size_t ws_size,
                              hipStream_t stream) {
    const float* embs = (const float*)d_in[0];
    const int*   ei0  = (const int*)d_in[1];
    const int*   ei1  = (const int*)d_in[2];
    const float* w_l0 = (const float*)d_in[3];
    const float* w_r0 = (const float*)d_in[4];
    const float* b0   = (const float*)d_in[5];
    const float* w_l1 = (const float*)d_in[6];
    const float* w_r1 = (const float*)d_in[7];
    const float* b1   = (const float*)d_in[8];
    float* out = (float*)d_out;

    const int N = in_sizes[0] / D;
    const int E = in_sizes[1] / 2;
    const int nb = (N + SCAN_CHUNK - 1) / SCAN_CHUNK;  // 98 for N=100000 (<=256)

    // ws layout (floats first, then ints):
    // agg [N*D] | h [N*D] | WT0 [32768] | WT1 [32768] |
    // row_ptr0 [N+1] | cursor0 [N] | edge_src0 [E] |
    // row_ptr1 [N+1] | cursor1 [N] | edge_src1 [E] | blk_sums [256]
    float* agg = (float*)d_ws;
    float* h   = agg + (size_t)N * D;
    float* WT0 = h + (size_t)N * D;
    float* WT1 = WT0 + 256 * 128;
    int* row_ptr0  = (int*)(WT1 + 256 * 128);
    int* cursor0   = row_ptr0 + (N + 1);
    int* edge_src0 = cursor0 + N;
    int* row_ptr1  = edge_src0 + E;
    int* cursor1   = row_ptr1 + (N + 1);
    int* edge_src1 = cursor1 + N;
    int* blk_sums  = edge_src1 + E;

    const int prep_grid = (256 * 128 + 255) / 256;
    const int edge_grid = (E + 255) / 256;
    const int agg_grid  = ((size_t)N * 64 + 255) / 256;
    const int gemm_grid = (N + 127) / 128;

    prep_weights<<<prep_grid, 256, 0, stream>>>(w_l0, w_r0, WT0);
    prep_weights<<<prep_grid, 256, 0, stream>>>(w_l1, w_r1, WT1);

    // ---- CSR build graph 0 ----
    hipMemsetAsync(cursor0, 0, (size_t)N * sizeof(int), stream);
    hist_kernel<<<edge_grid, 256, 0, stream>>>(ei0, E, cursor0);
    scan_phase_a<<<nb, 256, 0, stream>>>(cursor0, N, blk_sums);
    scan_phase_b<<<1, 256, 0, stream>>>(blk_sums, nb);
    scan_phase_c<<<nb, 256, 0, stream>>>(cursor0, N, E, blk_sums, row_ptr0);
    fill_kernel<<<edge_grid, 256, 0, stream>>>(ei0, E, cursor0, edge_src0);

    // ---- CSR build graph 1 ----
    hipMemsetAsync(cursor1, 0, (size_t)N * sizeof(int), stream);
    hist_kernel<<<edge_grid, 256, 0, stream>>>(ei1, E, cursor1);
    scan_phase_a<<<nb, 256, 0, stream>>>(cursor1, N, blk_sums);
    scan_phase_b<<<1, 256, 0, stream>>>(blk_sums, nb);
    scan_phase_c<<<nb, 256, 0, stream>>>(cursor1, N, E, blk_sums, row_ptr1);
    fill_kernel<<<edge_grid, 256, 0, stream>>>(ei1, E, cursor1, edge_src1);

    // ---- layer 0 ----
    agg_kernel<<<agg_grid, 256, 0, stream>>>(embs, row_ptr0, edge_src0, agg, N);
    sage_linear<true><<<gemm_grid, 256, 0, stream>>>(agg, embs, WT0, b0, h, N);

    // ---- layer 1 ----
    agg_kernel<<<agg_grid, 256, 0, stream>>>(h, row_ptr1, edge_src1, agg, N);
    sage_linear<false><<<gemm_grid, 256, 0, stream>>>(agg, h, WT1, b1, out, N);
}

// Round 4
// 762.602 us; speedup vs baseline: 7.6781x; 1.2574x over previous
//
#include <hip/hip_runtime.h>
#include <hip/hip_fp16.h>
#include <math.h>

#define D 128
#define SCAN_CHUNK 1024

typedef _Float16 half4v __attribute__((ext_vector_type(4)));
typedef _Float16 half8  __attribute__((ext_vector_type(8)));
typedef float    floatx16 __attribute__((ext_vector_type(16)));

// ---------------------------------------------------------------------------
// Cast fp32 -> fp16 (4 elems/thread).
// ---------------------------------------------------------------------------
__global__ __launch_bounds__(256) void cast_half(
        const float* __restrict__ x, _Float16* __restrict__ y, int n) {
    int i = blockIdx.x * 256 + threadIdx.x;
    int idx = i * 4;
    if (idx >= n) return;
    float4 v = *(const float4*)(x + idx);
    half4v h;
    h[0] = (_Float16)v.x; h[1] = (_Float16)v.y;
    h[2] = (_Float16)v.z; h[3] = (_Float16)v.w;
    *(half4v*)(y + idx) = h;
}

// ---------------------------------------------------------------------------
// Build B fragments pre-swizzled for v_mfma_f32_32x32x16_f16.
// Combined weight WT[k][c] = (k<128) ? w_l[c][k] : w_r[c][k-128], k in [0,256).
// Fragment f = ks*4+cb (ks=0..15 k-step, cb=0..3 col-block), lane l, elem j:
//   value = WT[ks*16 + (l>>5)*8 + j][cb*32 + (l&31)]
// stored at Bswz[f*512 + l*8 + j]  (each lane's 8 halfs contiguous = 16B).
// ---------------------------------------------------------------------------
__global__ __launch_bounds__(256) void prep_bswz(
        const float* __restrict__ wl, const float* __restrict__ wr,
        _Float16* __restrict__ B) {
    int idx = blockIdx.x * 256 + threadIdx.x;  // 64*512 = 32768
    if (idx >= 64 * 512) return;
    int j = idx & 7;
    int lane = (idx >> 3) & 63;
    int f = idx >> 9;
    int ks = f >> 2, cb = f & 3;
    int k = ks * 16 + (lane >> 5) * 8 + j;
    int c = cb * 32 + (lane & 31);
    float v = (k < 128) ? wl[c * 128 + k] : wr[c * 128 + (k - 128)];
    B[idx] = (_Float16)v;
}

// ---------------------------------------------------------------------------
// CSR build: histogram, 3-phase scan, fill (unchanged from round 3).
// ---------------------------------------------------------------------------
__global__ __launch_bounds__(256) void hist_kernel(
        const int* __restrict__ ei, int E, int* __restrict__ cursor) {
    int e = blockIdx.x * 256 + threadIdx.x;
    if (e >= E) return;
    atomicAdd(&cursor[ei[E + e]], 1);
}

__global__ __launch_bounds__(256) void scan_phase_a(
        const int* __restrict__ counts, int N, int* __restrict__ blk_sums) {
    __shared__ int red[256];
    int t = threadIdx.x;
    int base = blockIdx.x * SCAN_CHUNK + t * 4;
    int s = 0;
#pragma unroll
    for (int i = 0; i < 4; ++i) {
        int idx = base + i;
        if (idx < N) s += counts[idx];
    }
    red[t] = s;
    __syncthreads();
    for (int off = 128; off > 0; off >>= 1) {
        if (t < off) red[t] += red[t + off];
        __syncthreads();
    }
    if (t == 0) blk_sums[blockIdx.x] = red[0];
}

__global__ __launch_bounds__(256) void scan_phase_b(
        int* __restrict__ blk_sums, int nb) {
    __shared__ int part[256];
    int t = threadIdx.x;
    part[t] = (t < nb) ? blk_sums[t] : 0;
    __syncthreads();
    for (int off = 1; off < 256; off <<= 1) {
        int u = (t >= off) ? part[t - off] : 0;
        __syncthreads();
        part[t] += u;
        __syncthreads();
    }
    if (t < nb) blk_sums[t] = (t == 0) ? 0 : part[t - 1];
}

__global__ __launch_bounds__(256) void scan_phase_c(
        int* __restrict__ counts, int N, int E,
        const int* __restrict__ blk_sums, int* __restrict__ row_ptr) {
    __shared__ int part[256];
    int t = threadIdx.x;
    int base = blockIdx.x * SCAN_CHUNK + t * 4;
    int c[4];
    int s = 0;
#pragma unroll
    for (int i = 0; i < 4; ++i) {
        int idx = base + i;
        c[i] = (idx < N) ? counts[idx] : 0;
        s += c[i];
    }
    part[t] = s;
    __syncthreads();
    for (int off = 1; off < 256; off <<= 1) {
        int u = (t >= off) ? part[t - off] : 0;
        __syncthreads();
        part[t] += u;
        __syncthreads();
    }
    int run = blk_sums[blockIdx.x] + ((t == 0) ? 0 : part[t - 1]);
#pragma unroll
    for (int i = 0; i < 4; ++i) {
        int idx = base + i;
        if (idx < N) {
            row_ptr[idx] = run;
            counts[idx] = run;
            run += c[i];
        }
    }
    if (blockIdx.x == 0 && t == 0) row_ptr[N] = E;
}

__global__ __launch_bounds__(256) void fill_kernel(
        const int* __restrict__ ei, int E,
        int* __restrict__ cursor, int* __restrict__ edge_src) {
    int e = blockIdx.x * 256 + threadIdx.x;
    if (e >= E) return;
    int src = ei[e];
    int dst = ei[E + e];
    int pos = atomicAdd(&cursor[dst], 1);
    edge_src[pos] = src;
}

// ---------------------------------------------------------------------------
// Gather aggregation in fp16: one wave per node, lane holds a half2 (2 dims).
// agg[n] = mean_{src} x[src]; fp32 accumulation, fp16 output.
// ---------------------------------------------------------------------------
__global__ __launch_bounds__(256) void agg_half(
        const _Float16* __restrict__ x, const int* __restrict__ row_ptr,
        const int* __restrict__ edge_src, _Float16* __restrict__ agg, int N) {
    int gt = blockIdx.x * 256 + threadIdx.x;
    int w = gt >> 6;
    int lane = gt & 63;
    if (w >= N) return;
    int beg = row_ptr[w];
    int end = row_ptr[w + 1];
    const __half2* base = (const __half2*)x + lane;
    float ax = 0.0f, ay = 0.0f;
    int e = beg;
    for (; e + 4 <= end; e += 4) {
        int s0 = edge_src[e + 0];
        int s1 = edge_src[e + 1];
        int s2 = edge_src[e + 2];
        int s3 = edge_src[e + 3];
        float2 f0 = __half22float2(base[(size_t)s0 * 64]);
        float2 f1 = __half22float2(base[(size_t)s1 * 64]);
        float2 f2 = __half22float2(base[(size_t)s2 * 64]);
        float2 f3 = __half22float2(base[(size_t)s3 * 64]);
        ax += f0.x + f1.x + f2.x + f3.x;
        ay += f0.y + f1.y + f2.y + f3.y;
    }
    for (; e < end; ++e) {
        float2 f = __half22float2(base[(size_t)edge_src[e] * 64]);
        ax += f.x;
        ay += f.y;
    }
    int deg = end - beg;
    float inv = (deg > 0) ? 1.0f / (float)deg : 0.0f;
    ((__half2*)agg)[(size_t)w * 64 + lane] =
        __float22half2_rn(make_float2(ax * inv, ay * inv));
}

// ---------------------------------------------------------------------------
// MFMA SAGE linear: out[n][c] = sum_k [agg|x][n][k] * WT[k][c] + b[c] (+GELU).
// Block = 256 (4 waves), tile 128 nodes x 128 cols, K=256 in 2 phases
// (agg rows then x rows), each phase staged in LDS [128][132] halfs
// (stride 132 halfs = 264 B: rows 2 banks apart -> 2-way b64 reads, free).
// Wave w computes rows w*32..w*32+31, all 128 cols as 4 col-blocks of 32.
// B fragments come pre-swizzled from global (L2-resident, 16B/lane loads).
// C/D layout: col = lane&31, row = (reg&3) + 8*(reg>>2) + 4*(lane>>5).
// ---------------------------------------------------------------------------
template <bool GELU, typename OutT>
__global__ __launch_bounds__(256) void sage_mfma(
        const _Float16* __restrict__ aggh, const _Float16* __restrict__ xh,
        const _Float16* __restrict__ Bswz, const float* __restrict__ bias,
        OutT* __restrict__ out, int N) {
    __shared__ _Float16 a_lds[128 * 132];

    const int tid = threadIdx.x;
    const int n0 = blockIdx.x * 128;
    const int wave = tid >> 6;
    const int lane = tid & 63;
    const int l31 = lane & 31;
    const int lhi = lane >> 5;

    floatx16 acc[4];
#pragma unroll
    for (int cb = 0; cb < 4; ++cb)
#pragma unroll
        for (int r = 0; r < 16; ++r) acc[cb][r] = 0.0f;

    const _Float16* ap = a_lds + (wave * 32 + l31) * 132 + lhi * 8;

#pragma unroll
    for (int phase = 0; phase < 2; ++phase) {
        const _Float16* src = phase ? xh : aggh;

        __syncthreads();  // previous phase fully consumed
        // stage 128 rows x 128 halfs (32 KB): thread t -> row t>>1, half p=t&1
        {
            int r = tid >> 1;
            int p = tid & 1;
            _Float16* dstp = a_lds + r * 132 + p * 64;
            int gn = n0 + r;
            if (gn < N) {
                const float4* g = (const float4*)(src + (size_t)gn * 128 + p * 64);
#pragma unroll
                for (int j = 0; j < 8; ++j) {
                    float4 v = g[j];
                    float2* w2 = (float2*)(dstp + j * 8);
                    w2[0] = make_float2(v.x, v.y);
                    w2[1] = make_float2(v.z, v.w);
                }
            } else {
#pragma unroll
                for (int j = 0; j < 8; ++j) {
                    float2* w2 = (float2*)(dstp + j * 8);
                    w2[0] = make_float2(0.f, 0.f);
                    w2[1] = make_float2(0.f, 0.f);
                }
            }
        }
        __syncthreads();

        const _Float16* bbase = Bswz + ((size_t)phase * 8 * 4 * 512) + lane * 8;
#pragma unroll
        for (int ks = 0; ks < 8; ++ks) {
            half4v alo = *(const half4v*)(ap + ks * 16);
            half4v ahi = *(const half4v*)(ap + ks * 16 + 4);
            half8 afrag = __builtin_shufflevector(alo, ahi, 0, 1, 2, 3, 4, 5, 6, 7);
#pragma unroll
            for (int cb = 0; cb < 4; ++cb) {
                half8 bfrag = *(const half8*)(bbase + (ks * 4 + cb) * 512);
                acc[cb] = __builtin_amdgcn_mfma_f32_32x32x16_f16(
                    afrag, bfrag, acc[cb], 0, 0, 0);
            }
        }
    }

    // epilogue
#pragma unroll
    for (int cb = 0; cb < 4; ++cb) {
        int col = cb * 32 + l31;
        float bv = bias[col];
#pragma unroll
        for (int r = 0; r < 16; ++r) {
            int rowin = (r & 3) + 8 * (r >> 2) + 4 * lhi;
            int grow = n0 + wave * 32 + rowin;
            if (grow < N) {
                float v = acc[cb][r] + bv;
                if (GELU) v = 0.5f * v * (1.0f + erff(v * 0.70710678118654752f));
                out[(size_t)grow * 128 + col] = (OutT)v;
            }
        }
    }
}

// ---------------------------------------------------------------------------
extern "C" void kernel_launch(void* const* d_in, const int* in_sizes, int n_in,
                              void* d_out, int out_size, void* d_ws, size_t ws_size,
                              hipStream_t stream) {
    const float* embs = (const float*)d_in[0];
    const int*   ei0  = (const int*)d_in[1];
    const int*   ei1  = (const int*)d_in[2];
    const float* w_l0 = (const float*)d_in[3];
    const float* w_r0 = (const float*)d_in[4];
    const float* b0   = (const float*)d_in[5];
    const float* w_l1 = (const float*)d_in[6];
    const float* w_r1 = (const float*)d_in[7];
    const float* b1   = (const float*)d_in[8];
    float* out = (float*)d_out;

    const int N = in_sizes[0] / D;
    const int E = in_sizes[1] / 2;
    const int nb = (N + SCAN_CHUNK - 1) / SCAN_CHUNK;  // <=256

    // ws layout: x_h [N*128 h] | h_h [N*128 h] | agg_h [N*128 h] |
    //            Bswz0 [32768 h] | Bswz1 [32768 h] | (ints...)
    _Float16* x_h   = (_Float16*)d_ws;
    _Float16* h_h   = x_h + (size_t)N * D;
    _Float16* agg_h = h_h + (size_t)N * D;
    _Float16* Bswz0 = agg_h + (size_t)N * D;
    _Float16* Bswz1 = Bswz0 + 64 * 512;
    int* row_ptr0  = (int*)(Bswz1 + 64 * 512);
    int* cursor0   = row_ptr0 + (N + 1);
    int* edge_src0 = cursor0 + N;
    int* row_ptr1  = edge_src0 + E;
    int* cursor1   = row_ptr1 + (N + 1);
    int* edge_src1 = cursor1 + N;
    int* blk_sums  = edge_src1 + E;

    const int edge_grid = (E + 255) / 256;
    const int agg_grid  = ((size_t)N * 64 + 255) / 256;
    const int gemm_grid = (N + 127) / 128;
    const int cast_grid = ((size_t)N * D / 4 + 255) / 256;

    cast_half<<<cast_grid, 256, 0, stream>>>(embs, x_h, N * D);
    prep_bswz<<<128, 256, 0, stream>>>(w_l0, w_r0, Bswz0);
    prep_bswz<<<128, 256, 0, stream>>>(w_l1, w_r1, Bswz1);

    // ---- CSR build graph 0 ----
    hipMemsetAsync(cursor0, 0, (size_t)N * sizeof(int), stream);
    hist_kernel<<<edge_grid, 256, 0, stream>>>(ei0, E, cursor0);
    scan_phase_a<<<nb, 256, 0, stream>>>(cursor0, N, blk_sums);
    scan_phase_b<<<1, 256, 0, stream>>>(blk_sums, nb);
    scan_phase_c<<<nb, 256, 0, stream>>>(cursor0, N, E, blk_sums, row_ptr0);
    fill_kernel<<<edge_grid, 256, 0, stream>>>(ei0, E, cursor0, edge_src0);

    // ---- CSR build graph 1 ----
    hipMemsetAsync(cursor1, 0, (size_t)N * sizeof(int), stream);
    hist_kernel<<<edge_grid, 256, 0, stream>>>(ei1, E, cursor1);
    scan_phase_a<<<nb, 256, 0, stream>>>(cursor1, N, blk_sums);
    scan_phase_b<<<1, 256, 0, stream>>>(blk_sums, nb);
    scan_phase_c<<<nb, 256, 0, stream>>>(cursor1, N, E, blk_sums, row_ptr1);
    fill_kernel<<<edge_grid, 256, 0, stream>>>(ei1, E, cursor1, edge_src1);

    // ---- layer 0 ----
    agg_half<<<agg_grid, 256, 0, stream>>>(x_h, row_ptr0, edge_src0, agg_h, N);
    sage_mfma<true, _Float16><<<gemm_grid, 256, 0, stream>>>(
        agg_h, x_h, Bswz0, b0, h_h, N);

    // ---- layer 1 ----
    agg_half<<<agg_grid, 256, 0, stream>>>(h_h, row_ptr1, edge_src1, agg_h, N);
    sage_mfma<false, float><<<gemm_grid, 256, 0, stream>>>(
        agg_h, h_h, Bswz1, b1, out, N);
}